// Round 7
// baseline (132.840 us; speedup 1.0000x reference)
//
#include <hip/hip_runtime.h>
#include <hip/hip_bf16.h>
#include <stdint.h>

#define BB 2
#define SS 4096
#define EE 640
#define HH 4
#define DD 256
#define WIN 512

typedef __attribute__((ext_vector_type(8))) short bv8;    // 8 bf16 (4 VGPR)
typedef __attribute__((ext_vector_type(4))) float fv4;
typedef __attribute__((ext_vector_type(16))) float fv16;  // 32x32 accumulator

__device__ __forceinline__ unsigned short f2b(float f) {
  union { float f; unsigned u; } a; a.f = f;
  unsigned r = a.u + 0x7fffu + ((a.u >> 16) & 1u);   // RNE
  return (unsigned short)(r >> 16);
}
__device__ __forceinline__ float b2f(unsigned short s) {
  union { unsigned u; float f; } a; a.u = ((unsigned)s) << 16;
  return a.f;
}
// pack two f32 -> one u32 of 2xbf16 via HW cvt (lo=e0, hi=e1)
__device__ __forceinline__ unsigned cvtpk(float e0, float e1) {
  unsigned r;
  asm("v_cvt_pk_bf16_f32 %0, %1, %2" : "=v"(r) : "v"(e0), "v"(e1));
  return r;
}

typedef const __attribute__((address_space(1))) unsigned int* as1u;
typedef __attribute__((address_space(3))) unsigned int* as3u;
__device__ __forceinline__ void gld16(const unsigned short* g, unsigned short* l) {
  // async global->LDS, 16B/lane; LDS dst = wave-uniform base + lane*16
  __builtin_amdgcn_global_load_lds((as1u)(const void*)g, (as3u)(void*)l, 16, 0, 0);
}

// ---------------- f32 -> bf16 cast (x) ----------------
__global__ __launch_bounds__(256) void k_cast_bf16(const float* __restrict__ src,
                                                   unsigned short* __restrict__ dst, int n4) {
  int i = blockIdx.x * 256 + threadIdx.x;
  if (i >= n4) return;
  fv4 v = ((const fv4*)src)[i];
  ushort4 o; o.x = f2b(v.x); o.y = f2b(v.y); o.z = f2b(v.z); o.w = f2b(v.w);
  ((ushort4*)dst)[i] = o;
}

// ---------------- tiled transpose + cast to bf16 ----------------
template <typename T>
__global__ __launch_bounds__(256) void k_transpose_bf16(const T* __restrict__ src,
    unsigned short* __restrict__ dst, int sstride, int dstride) {
  __shared__ float tile[32][33];
  int r0 = blockIdx.x * 32, c0 = blockIdx.y * 32;
  int t = threadIdx.x;
  int rr = t >> 3, cc = (t & 7) * 4;
  const T* p = src + (size_t)(r0 + rr) * sstride + c0 + cc;
  float v[4];
  if constexpr (sizeof(T) == 4) {
    fv4 x = *(const fv4*)p;
    v[0] = x.x; v[1] = x.y; v[2] = x.z; v[3] = x.w;
  } else {
    ushort4 x = *(const ushort4*)p;
    v[0] = b2f(x.x); v[1] = b2f(x.y); v[2] = b2f(x.z); v[3] = b2f(x.w);
  }
#pragma unroll
  for (int i = 0; i < 4; ++i) tile[cc + i][rr] = v[i];
  __syncthreads();
  ushort4 o;
  o.x = f2b(tile[rr][cc + 0]); o.y = f2b(tile[rr][cc + 1]);
  o.z = f2b(tile[rr][cc + 2]); o.w = f2b(tile[rr][cc + 3]);
  *(ushort4*)(dst + (size_t)(c0 + rr) * dstride + r0 + cc) = o;
}

// ---------------- bf16 GEMM (m97 structure): C(MxN) = A(MxK) * Bt(NxK)^T ----
template <bool OUT_BF16, int BN>
__global__ __launch_bounds__(256) void k_gemm(const unsigned short* __restrict__ A,
    const unsigned short* __restrict__ Bt, void* __restrict__ Cp,
    int M, int N, int K, int nt_n) {
  __shared__ unsigned short la[128 * 32];
  __shared__ unsigned short lb[BN * 32];
  const int bid = blockIdx.x;
  const int gidx = (bid & 7) * (gridDim.x >> 3) + (bid >> 3);
  const int m0 = (gidx / nt_n) * 128, n0 = (gidx % nt_n) * BN;
  const int tid = threadIdx.x, lane = tid & 63, wave = tid >> 6;
  const int g = lane >> 4, lr = lane & 15;
  constexpr int MI = (BN == 128) ? 4 : 2;
  const int wm = (BN == 128) ? (wave >> 1) * 64 : wave * 32;
  const int wn = (BN == 128) ? (wave & 1) * 64 : 0;
  fv4 acc[MI][4] = {};
  const int srow = wave * 32 + (lane >> 2);
  const int sch = (lane & 3) * 8;
  const unsigned short* ga0 = A + (size_t)(m0 + srow) * K + sch;
  unsigned short* lad = la + wave * 1024;
  const int srowb = (BN == 128) ? srow : (wave * 16 + (lane >> 2));
  const unsigned short* gb0 = Bt + (size_t)(n0 + srowb) * K + sch;
  unsigned short* lbd = lb + ((BN == 128) ? wave * 1024 : wave * 512);
  for (int k0 = 0; k0 < K; k0 += 32) {
    __syncthreads();
    gld16(ga0 + k0, lad);
    gld16(ga0 + (size_t)16 * K + k0, lad + 512);
    gld16(gb0 + k0, lbd);
    if constexpr (BN == 128) gld16(gb0 + (size_t)16 * K + k0, lbd + 512);
    __syncthreads();
    bv8 af[MI], bf[4];
#pragma unroll
    for (int mi = 0; mi < MI; ++mi) af[mi] = *(const bv8*)(la + (wm + mi * 16 + lr) * 32 + g * 8);
#pragma unroll
    for (int ni = 0; ni < 4; ++ni) bf[ni] = *(const bv8*)(lb + (wn + ni * 16 + lr) * 32 + g * 8);
    __builtin_amdgcn_s_setprio(1);
#pragma unroll
    for (int mi = 0; mi < MI; ++mi)
#pragma unroll
      for (int ni = 0; ni < 4; ++ni)
        acc[mi][ni] = __builtin_amdgcn_mfma_f32_16x16x32_bf16(af[mi], bf[ni], acc[mi][ni], 0, 0, 0);
    __builtin_amdgcn_s_setprio(0);
  }
#pragma unroll
  for (int mi = 0; mi < MI; ++mi) {
#pragma unroll
    for (int r = 0; r < 4; ++r) {
      size_t row = (size_t)(m0 + wm + mi * 16 + g * 4 + r);
#pragma unroll
      for (int ni = 0; ni < 4; ++ni) {
        int col = n0 + wn + ni * 16 + lr;
        float val = acc[mi][ni][r];
        if constexpr (OUT_BF16)
          ((unsigned short*)Cp)[row * N + col] = f2b(val);
        else
          ((float*)Cp)[row * N + col] = val;
      }
    }
  }
}

// ---------------- rmsnorm + rope, bf16 out ----------------------------------
// q scale folds SCALING (1/16) AND log2(e): attn softmax runs in exp2 domain.
__global__ __launch_bounds__(320) void k_normrope(const unsigned short* __restrict__ qkv,
    const float* __restrict__ cosp, const float* __restrict__ sinp,
    const float* __restrict__ qsc, const float* __restrict__ ksc,
    unsigned short* __restrict__ qo, unsigned short* __restrict__ ko) {
  int m = blockIdx.x;
  int b = m >> 12, s = m & 4095;
  int wave = threadIdx.x >> 6, lane = threadIdx.x & 63;
  bool isq = wave < 4;
  const unsigned short* src = qkv + (size_t)m * 1536 + (isq ? wave * 256 : 1024);
  const float* scp = isq ? qsc : ksc;
  int d0 = lane * 4;
  ushort4 raw = *(const ushort4*)(src + d0);
  float x0 = b2f(raw.x), x1 = b2f(raw.y), x2 = b2f(raw.z), x3 = b2f(raw.w);
  float ss = x0 * x0 + x1 * x1 + x2 * x2 + x3 * x3;
#pragma unroll
  for (int off = 1; off < 64; off <<= 1) ss += __shfl_xor(ss, off, 64);
  float rs = rsqrtf(ss * (1.0f / 256.0f) + 1e-6f);
  fv4 sc = *(const fv4*)(scp + d0);
  float n0 = x0 * rs * (1.0f + sc.x);
  float n1 = x1 * rs * (1.0f + sc.y);
  float n2 = x2 * rs * (1.0f + sc.z);
  float n3 = x3 * rs * (1.0f + sc.w);
  float p0 = __shfl_xor(n0, 32, 64);
  float p1 = __shfl_xor(n1, 32, 64);
  float p2 = __shfl_xor(n2, 32, 64);
  float p3 = __shfl_xor(n3, 32, 64);
  float sgn = (lane < 32) ? -1.0f : 1.0f;
  fv4 c4 = *(const fv4*)(cosp + (size_t)s * 256 + d0);
  fv4 s4 = *(const fv4*)(sinp + (size_t)s * 256 + d0);
  float mult = isq ? (0.0625f * 1.44269504f) : 1.0f;   // SCALING * log2(e) into q
  float o0 = (n0 * c4.x + sgn * p0 * s4.x) * mult;
  float o1 = (n1 * c4.y + sgn * p1 * s4.y) * mult;
  float o2 = (n2 * c4.z + sgn * p2 * s4.z) * mult;
  float o3 = (n3 * c4.w + sgn * p3 * s4.w) * mult;
  ushort4 o; o.x = f2b(o0); o.y = f2b(o1); o.z = f2b(o2); o.w = f2b(o3);
  unsigned short* dst = isq
      ? qo + ((size_t)(b * HH + wave) * SS + s) * 256 + d0
      : ko + ((size_t)b * SS + s) * 256 + d0;
  *(ushort4*)dst = o;
}

// ---------------- flash attention, sliding window 512 ----------------------
// MQA-shared: block = 512 thr = 8 waves = 4 heads x 2 key-halves over a
// 32-q-row slab; K/V staged once serve all 4 heads. 32x32x16 MFMA, swapped
// operands (S^T = mfma(K,Q)), in-register P via cvt_pk + permlane32_swap.
// Softmax in exp2 domain (log2e folded into q); scores*log2e bounded by 23.1.
// QK accumulates in TWO chains for MFMA ILP. Fixed-max -> key-half partials
// linear; combined once at the end. K+V double-buffered via global_load_lds
// with both-sides XOR swizzle; 1 barrier/tile.
__global__ __launch_bounds__(512, 2) void k_attn(const unsigned short* __restrict__ q,
    const unsigned short* __restrict__ kg, const unsigned short* __restrict__ vtg,
    unsigned short* __restrict__ att) {
  __shared__ __align__(16) char ldsbuf[133120];   // K/V tiles; reused as combine buf
  __shared__ float lsb[4][32];
  unsigned short* kt = (unsigned short*)ldsbuf;           // [2][64*256]
  unsigned short* vl = (unsigned short*)ldsbuf + 32768;   // [2][256*64]
  const int bid = blockIdx.x;
  const int gidx = (bid & 7) * 32 + (bid >> 3);   // XCD-chunked (256 blocks)
  const int b = gidx >> 7;
  const int i0 = (gidx & 127) * 32;
  const int tid = threadIdx.x, wave = tid >> 6, lane = tid & 63;
  const int h = wave >> 1, ks = wave & 1;
  const int hi = lane >> 5, l31 = lane & 31;
  // Q B-fragments: B[k][q], col=q=lane&31, k = m*16 + hi*8 + e
  bv8 qf[16];
  {
    const unsigned short* qp = q + ((size_t)(b * HH + h) * SS + i0 + l31) * 256;
#pragma unroll
    for (int m = 0; m < 16; ++m) qf[m] = *(const bv8*)(qp + m * 16 + hi * 8);
  }
  fv16 po[8] = {};
  float lsp = 0.f;
  const int t0 = (i0 >= WIN) ? ((i0 - WIN + 1) >> 6) : 0;
  const int t1 = i0 >> 6;
  const unsigned short* kb = kg + (size_t)b * SS * 256;
  const unsigned short* vb = vtg + (size_t)b * 256 * SS;
  auto stageK = [&](int t, int pp) {
    const unsigned short* kbase = kb + (size_t)t * 64 * 256;
    unsigned short* dst = kt + pp * 16384;
#pragma unroll
    for (int c = 0; c < 4; ++c) {
      int slot = c * 512 + tid;
      int row = slot >> 5, s = slot & 31;
      gld16(kbase + (size_t)row * 256 + ((s ^ (row & 7)) * 8),
            dst + (c * 512 + wave * 64) * 8);
    }
  };
  auto stageV = [&](int t, int pp) {
    const unsigned short* vbase = vb + (size_t)t * 64;
    unsigned short* dst = vl + pp * 16384;
#pragma unroll
    for (int c = 0; c < 4; ++c) {
      int slot = c * 512 + tid;
      int d_ = slot >> 3, s = slot & 7;
      gld16(vbase + (size_t)d_ * SS + ((s ^ (d_ & 7)) * 8),
            dst + (c * 512 + wave * 64) * 8);
    }
  };
  stageK(t0, 0); stageV(t0, 0);
  int p = 0;
  const int krow = ks * 32 + l31;        // K-frag row (key within tile)
  const int krx = krow & 7;
  const int vrx = l31 & 7;               // V-frag row&7 (d_&7 == l31&7)
  const float FSUB = 16.5f * 1.44269504f;
  for (int t = t0; t <= t1; ++t) {
    __syncthreads();   // drains staging of buf p; prior iter's reads of p^1 done
    if (t < t1) { stageK(t + 1, p ^ 1); stageV(t + 1, p ^ 1); }
    // ---- QK^T (swapped): S^T[key][q], two accumulation chains for ILP ----
    fv16 sa0 = {}, sa1 = {};
    const unsigned short* ktp = kt + p * 16384 + krow * 256;
    __builtin_amdgcn_s_setprio(1);
#pragma unroll
    for (int m = 0; m < 8; ++m) {
      bv8 kfa = *(const bv8*)(ktp + (((m * 2 + hi) ^ krx) * 8));
      bv8 kfb = *(const bv8*)(ktp + ((((m + 8) * 2 + hi) ^ krx) * 8));
      sa0 = __builtin_amdgcn_mfma_f32_32x32x16_bf16(kfa, qf[m], sa0, 0, 0, 0);
      sa1 = __builtin_amdgcn_mfma_f32_32x32x16_bf16(kfb, qf[m + 8], sa1, 0, 0, 0);
    }
    __builtin_amdgcn_s_setprio(0);
    fv16 sa = sa0 + sa1;
    // ---- mask + exp2 (fixed max) ----
    const int jb = t * 64;
    const int kb0 = jb + ks * 32;
    const bool nm = (kb0 + 31 > i0) || (i0 + 31 - kb0 >= WIN);
    if (nm) {
      const int qa = i0 + l31;
#pragma unroll
      for (int r = 0; r < 16; ++r) {
        int j = kb0 + (r & 3) + 8 * (r >> 2) + 4 * hi;
        if (j > qa || qa - j >= WIN) sa[r] = -1e30f;
      }
    }
    unsigned a[8];
#pragma unroll
    for (int i = 0; i < 8; ++i) {
      float e0 = exp2f(sa[2 * i] - FSUB);
      float e1 = exp2f(sa[2 * i + 1] - FSUB);
      lsp += e0 + e1;
      a[i] = cvtpk(e0, e1);
    }
    // ---- P^T B-frag assembly via permlane32_swap (verified mapping) ----
    const unsigned short* vlp = vl + p * 16384;
    __builtin_amdgcn_s_setprio(1);
#pragma unroll
    for (int m2 = 0; m2 < 2; ++m2) {
      auto r02 = __builtin_amdgcn_permlane32_swap(a[m2 * 4 + 0], a[m2 * 4 + 2], false, false);
      auto r13 = __builtin_amdgcn_permlane32_swap(a[m2 * 4 + 1], a[m2 * 4 + 3], false, false);
      union { unsigned u[4]; bv8 v; } pf;
      pf.u[0] = r02[0]; pf.u[1] = r13[0]; pf.u[2] = r02[1]; pf.u[3] = r13[1];
      const int slot = (ks * 4 + m2 * 2 + hi) ^ vrx;
#pragma unroll
      for (int ds_ = 0; ds_ < 8; ++ds_) {
        bv8 vf = *(const bv8*)(vlp + (ds_ * 32 + l31) * 64 + slot * 8);
        po[ds_] = __builtin_amdgcn_mfma_f32_32x32x16_bf16(vf, pf.v, po[ds_], 0, 0, 0);
      }
    }
    __builtin_amdgcn_s_setprio(0);
    p ^= 1;
  }
  // ---- combine the two key-halves (fixed-max partials are linear) ----
  float lsfull = lsp + __shfl_xor(lsp, 32, 64);
  __syncthreads();
  float* cb = (float*)ldsbuf;            // rows 128 (h*32+q) x stride 260 f32
  if (ks == 1) {
#pragma unroll
    for (int ds_ = 0; ds_ < 8; ++ds_)
#pragma unroll
      for (int j = 0; j < 4; ++j) {
        int d0 = ds_ * 32 + 8 * j + 4 * hi;
        fv4 v4; v4[0] = po[ds_][4 * j]; v4[1] = po[ds_][4 * j + 1];
        v4[2] = po[ds_][4 * j + 2]; v4[3] = po[ds_][4 * j + 3];
        *(fv4*)(cb + (h * 32 + l31) * 260 + d0) = v4;
      }
    if (lane < 32) lsb[h][lane] = lsfull;
  }
  __syncthreads();
  if (ks == 0) {
    float total = lsfull + lsb[h][l31];
    float inv = 1.0f / total;
    unsigned short* op = att + ((size_t)b * SS + i0 + l31) * 1024 + h * 256;
#pragma unroll
    for (int ds_ = 0; ds_ < 8; ++ds_)
#pragma unroll
      for (int j = 0; j < 4; ++j) {
        int d0 = ds_ * 32 + 8 * j + 4 * hi;
        fv4 v4 = *(const fv4*)(cb + (h * 32 + l31) * 260 + d0);
        ushort4 o;
        o.x = f2b((po[ds_][4 * j] + v4[0]) * inv);
        o.y = f2b((po[ds_][4 * j + 1] + v4[1]) * inv);
        o.z = f2b((po[ds_][4 * j + 2] + v4[2]) * inv);
        o.w = f2b((po[ds_][4 * j + 3] + v4[3]) * inv);
        *(ushort4*)(op + d0) = o;
      }
  }
}

extern "C" void kernel_launch(void* const* d_in, const int* in_sizes, int n_in,
                              void* d_out, int out_size, void* d_ws, size_t ws_size,
                              hipStream_t stream) {
  const float* x    = (const float*)d_in[0];
  // d_in[1] = mask (computed analytically)
  const float* cosp = (const float*)d_in[2];
  const float* sinp = (const float*)d_in[3];
  const float* Wq   = (const float*)d_in[4];
  const float* Wk   = (const float*)d_in[5];
  const float* Wv   = (const float*)d_in[6];
  const float* Wo   = (const float*)d_in[7];
  const float* qsc  = (const float*)d_in[8];
  const float* ksc  = (const float*)d_in[9];
  float* out = (float*)d_out;
  char* ws = (char*)d_ws;

  unsigned short* xb   = (unsigned short*)(ws);               // 8192x640 bf16
  unsigned short* wqkv = (unsigned short*)(ws + 10485760);    // 1536x640 bf16 (W^T)
  unsigned short* wo   = (unsigned short*)(ws + 12451840);    // 640x1024 bf16 (Wo^T)
  unsigned short* qkv  = (unsigned short*)(ws + 13762560);    // 8192x1536 bf16
  unsigned short* qb   = (unsigned short*)(ws + 38928384);    // (B,H,S,D) bf16
  unsigned short* kbuf = (unsigned short*)(ws + 55705600);    // (B,S,D) bf16
  unsigned short* vt   = (unsigned short*)(ws + 59899904);    // (B,D,S) bf16
  unsigned short* attb = (unsigned short*)(ws + 64094208);    // (B,S,H*D) bf16

  k_cast_bf16<<<5120, 256, 0, stream>>>(x, xb, 1310720);
  k_transpose_bf16<float><<<dim3(20, 32), 256, 0, stream>>>(Wq, wqkv, 1024, 640);
  k_transpose_bf16<float><<<dim3(20, 8), 256, 0, stream>>>(Wk, wqkv + 1024 * 640, 256, 640);
  k_transpose_bf16<float><<<dim3(20, 8), 256, 0, stream>>>(Wv, wqkv + 1280 * 640, 256, 640);
  k_transpose_bf16<float><<<dim3(32, 20), 256, 0, stream>>>(Wo, wo, 640, 1024);
  k_gemm<true, 128><<<768, 256, 0, stream>>>(xb, wqkv, qkv, 8192, 1536, 640, 12);
  k_normrope<<<8192, 320, 0, stream>>>(qkv, cosp, sinp, qsc, ksc, qb, kbuf);
  k_transpose_bf16<unsigned short><<<dim3(128, 8), 256, 0, stream>>>(qkv + 1280, vt, 1536, 4096);
  k_transpose_bf16<unsigned short><<<dim3(128, 8), 256, 0, stream>>>(
      qkv + (size_t)4096 * 1536 + 1280, vt + (size_t)256 * 4096, 1536, 4096);
  k_attn<<<256, 512, 0, stream>>>(qb, kbuf, vt, attb);
  k_gemm<false, 64><<<640, 256, 0, stream>>>(attb, wo, out, 8192, 640, 1024, 10);
}

// Round 8
// 129.872 us; speedup vs baseline: 1.0228x; 1.0228x over previous
//
#include <hip/hip_runtime.h>
#include <hip/hip_bf16.h>
#include <stdint.h>

#define BB 2
#define SS 4096
#define EE 640
#define HH 4
#define DD 256
#define WIN 512

typedef __attribute__((ext_vector_type(8))) short bv8;    // 8 bf16 (4 VGPR)
typedef __attribute__((ext_vector_type(4))) float fv4;
typedef __attribute__((ext_vector_type(16))) float fv16;  // 32x32 accumulator

__device__ __forceinline__ unsigned short f2b(float f) {
  union { float f; unsigned u; } a; a.f = f;
  unsigned r = a.u + 0x7fffu + ((a.u >> 16) & 1u);   // RNE
  return (unsigned short)(r >> 16);
}
__device__ __forceinline__ float b2f(unsigned short s) {
  union { unsigned u; float f; } a; a.u = ((unsigned)s) << 16;
  return a.f;
}
__device__ __forceinline__ unsigned pk2(float lo, float hi_) {
  return (unsigned)f2b(lo) | ((unsigned)f2b(hi_) << 16);
}

typedef const __attribute__((address_space(1))) unsigned int* as1u;
typedef __attribute__((address_space(3))) unsigned int* as3u;
__device__ __forceinline__ void gld16(const unsigned short* g, unsigned short* l) {
  // async global->LDS, 16B/lane; LDS dst = wave-uniform base + lane*16
  __builtin_amdgcn_global_load_lds((as1u)(const void*)g, (as3u)(void*)l, 16, 0, 0);
}

// ---------------- f32 -> bf16 cast (x) ----------------
__global__ __launch_bounds__(256) void k_cast_bf16(const float* __restrict__ src,
                                                   unsigned short* __restrict__ dst, int n4) {
  int i = blockIdx.x * 256 + threadIdx.x;
  if (i >= n4) return;
  fv4 v = ((const fv4*)src)[i];
  ushort4 o; o.x = f2b(v.x); o.y = f2b(v.y); o.z = f2b(v.z); o.w = f2b(v.w);
  ((ushort4*)dst)[i] = o;
}

// ---------------- tiled transpose + cast to bf16 ----------------
template <typename T>
__global__ __launch_bounds__(256) void k_transpose_bf16(const T* __restrict__ src,
    unsigned short* __restrict__ dst, int sstride, int dstride) {
  __shared__ float tile[32][33];
  int r0 = blockIdx.x * 32, c0 = blockIdx.y * 32;
  int t = threadIdx.x;
  int rr = t >> 3, cc = (t & 7) * 4;
  const T* p = src + (size_t)(r0 + rr) * sstride + c0 + cc;
  float v[4];
  if constexpr (sizeof(T) == 4) {
    fv4 x = *(const fv4*)p;
    v[0] = x.x; v[1] = x.y; v[2] = x.z; v[3] = x.w;
  } else {
    ushort4 x = *(const ushort4*)p;
    v[0] = b2f(x.x); v[1] = b2f(x.y); v[2] = b2f(x.z); v[3] = b2f(x.w);
  }
#pragma unroll
  for (int i = 0; i < 4; ++i) tile[cc + i][rr] = v[i];
  __syncthreads();
  ushort4 o;
  o.x = f2b(tile[rr][cc + 0]); o.y = f2b(tile[rr][cc + 1]);
  o.z = f2b(tile[rr][cc + 2]); o.w = f2b(tile[rr][cc + 3]);
  *(ushort4*)(dst + (size_t)(c0 + rr) * dstride + r0 + cc) = o;
}

// ---------------- bf16 GEMM (m97 structure): C(MxN) = A(MxK) * Bt(NxK)^T ----
template <bool OUT_BF16, int BN>
__global__ __launch_bounds__(256) void k_gemm(const unsigned short* __restrict__ A,
    const unsigned short* __restrict__ Bt, void* __restrict__ Cp,
    int M, int N, int K, int nt_n) {
  __shared__ unsigned short la[128 * 32];
  __shared__ unsigned short lb[BN * 32];
  const int bid = blockIdx.x;
  const int gidx = (bid & 7) * (gridDim.x >> 3) + (bid >> 3);
  const int m0 = (gidx / nt_n) * 128, n0 = (gidx % nt_n) * BN;
  const int tid = threadIdx.x, lane = tid & 63, wave = tid >> 6;
  const int g = lane >> 4, lr = lane & 15;
  constexpr int MI = (BN == 128) ? 4 : 2;
  const int wm = (BN == 128) ? (wave >> 1) * 64 : wave * 32;
  const int wn = (BN == 128) ? (wave & 1) * 64 : 0;
  fv4 acc[MI][4] = {};
  const int srow = wave * 32 + (lane >> 2);
  const int sch = (lane & 3) * 8;
  const unsigned short* ga0 = A + (size_t)(m0 + srow) * K + sch;
  unsigned short* lad = la + wave * 1024;
  const int srowb = (BN == 128) ? srow : (wave * 16 + (lane >> 2));
  const unsigned short* gb0 = Bt + (size_t)(n0 + srowb) * K + sch;
  unsigned short* lbd = lb + ((BN == 128) ? wave * 1024 : wave * 512);
  for (int k0 = 0; k0 < K; k0 += 32) {
    __syncthreads();
    gld16(ga0 + k0, lad);
    gld16(ga0 + (size_t)16 * K + k0, lad + 512);
    gld16(gb0 + k0, lbd);
    if constexpr (BN == 128) gld16(gb0 + (size_t)16 * K + k0, lbd + 512);
    __syncthreads();
    bv8 af[MI], bf[4];
#pragma unroll
    for (int mi = 0; mi < MI; ++mi) af[mi] = *(const bv8*)(la + (wm + mi * 16 + lr) * 32 + g * 8);
#pragma unroll
    for (int ni = 0; ni < 4; ++ni) bf[ni] = *(const bv8*)(lb + (wn + ni * 16 + lr) * 32 + g * 8);
    __builtin_amdgcn_s_setprio(1);
#pragma unroll
    for (int mi = 0; mi < MI; ++mi)
#pragma unroll
      for (int ni = 0; ni < 4; ++ni)
        acc[mi][ni] = __builtin_amdgcn_mfma_f32_16x16x32_bf16(af[mi], bf[ni], acc[mi][ni], 0, 0, 0);
    __builtin_amdgcn_s_setprio(0);
  }
#pragma unroll
  for (int mi = 0; mi < MI; ++mi) {
#pragma unroll
    for (int r = 0; r < 4; ++r) {
      size_t row = (size_t)(m0 + wm + mi * 16 + g * 4 + r);
#pragma unroll
      for (int ni = 0; ni < 4; ++ni) {
        int col = n0 + wn + ni * 16 + lr;
        float val = acc[mi][ni][r];
        if constexpr (OUT_BF16)
          ((unsigned short*)Cp)[row * N + col] = f2b(val);
        else
          ((float*)Cp)[row * N + col] = val;
      }
    }
  }
}

// ---------------- rmsnorm + rope, bf16 out ----------------------------------
// q scale folds SCALING (1/16) AND log2(e): attn softmax runs in exp2 domain.
__global__ __launch_bounds__(320) void k_normrope(const unsigned short* __restrict__ qkv,
    const float* __restrict__ cosp, const float* __restrict__ sinp,
    const float* __restrict__ qsc, const float* __restrict__ ksc,
    unsigned short* __restrict__ qo, unsigned short* __restrict__ ko) {
  int m = blockIdx.x;
  int b = m >> 12, s = m & 4095;
  int wave = threadIdx.x >> 6, lane = threadIdx.x & 63;
  bool isq = wave < 4;
  const unsigned short* src = qkv + (size_t)m * 1536 + (isq ? wave * 256 : 1024);
  const float* scp = isq ? qsc : ksc;
  int d0 = lane * 4;
  ushort4 raw = *(const ushort4*)(src + d0);
  float x0 = b2f(raw.x), x1 = b2f(raw.y), x2 = b2f(raw.z), x3 = b2f(raw.w);
  float ss = x0 * x0 + x1 * x1 + x2 * x2 + x3 * x3;
#pragma unroll
  for (int off = 1; off < 64; off <<= 1) ss += __shfl_xor(ss, off, 64);
  float rs = rsqrtf(ss * (1.0f / 256.0f) + 1e-6f);
  fv4 sc = *(const fv4*)(scp + d0);
  float n0 = x0 * rs * (1.0f + sc.x);
  float n1 = x1 * rs * (1.0f + sc.y);
  float n2 = x2 * rs * (1.0f + sc.z);
  float n3 = x3 * rs * (1.0f + sc.w);
  float p0 = __shfl_xor(n0, 32, 64);
  float p1 = __shfl_xor(n1, 32, 64);
  float p2 = __shfl_xor(n2, 32, 64);
  float p3 = __shfl_xor(n3, 32, 64);
  float sgn = (lane < 32) ? -1.0f : 1.0f;
  fv4 c4 = *(const fv4*)(cosp + (size_t)s * 256 + d0);
  fv4 s4 = *(const fv4*)(sinp + (size_t)s * 256 + d0);
  float mult = isq ? (0.0625f * 1.44269504f) : 1.0f;   // SCALING * log2(e) into q
  float o0 = (n0 * c4.x + sgn * p0 * s4.x) * mult;
  float o1 = (n1 * c4.y + sgn * p1 * s4.y) * mult;
  float o2 = (n2 * c4.z + sgn * p2 * s4.z) * mult;
  float o3 = (n3 * c4.w + sgn * p3 * s4.w) * mult;
  ushort4 o; o.x = f2b(o0); o.y = f2b(o1); o.z = f2b(o2); o.w = f2b(o3);
  unsigned short* dst = isq
      ? qo + ((size_t)(b * HH + wave) * SS + s) * 256 + d0
      : ko + ((size_t)b * SS + s) * 256 + d0;
  *(ushort4*)dst = o;
}

// ---------------- flash attention, sliding window 512 ----------------------
// 2 blocks/CU anti-phase structure: block = 4 waves = 2 heads x 2 key-halves
// over a 32-q-row slab; grid = 2 head-pairs x 128 slabs x 2 batch = 512 blocks
// -> 2 co-resident blocks per CU. K/V SINGLE-buffered (64 KB): while one
// block drains its stage (vmcnt0+barrier over only 4 waves), the other block
// computes. 32x32x16 MFMA, swapped operands (S^T = mfma(K,Q)), in-register P
// via manual bf16 pack + permlane32_swap. Softmax in exp2 domain (log2e
// folded into q upstream); fixed max (|score*log2e| <= 23.1 by Cauchy-Schwarz
// on RMSNorm'd vectors). Key-half partials combined once at the end through a
// packed-bf16 LDS buffer (stride 133 u32 -> conflict-free).
__global__ __launch_bounds__(256, 2) void k_attn(const unsigned short* __restrict__ q,
    const unsigned short* __restrict__ kg, const unsigned short* __restrict__ vtg,
    unsigned short* __restrict__ att) {
  __shared__ __align__(16) unsigned short kt[64 * 256];   // 32 KB [key][d] swizzled
  __shared__ __align__(16) unsigned short vl[256 * 64];   // 32 KB [d][key] swizzled
  __shared__ float lsb[2][32];
  const int bid = blockIdx.x;
  const int gidx = (bid & 7) * 64 + (bid >> 3);   // XCD-chunked (512 = 8 x 64)
  const int b = gidx >> 8;
  const int slab = (gidx & 255) >> 1;
  const int hp = gidx & 1;
  const int i0 = slab * 32;
  const int tid = threadIdx.x, wave = tid >> 6, lane = tid & 63;
  const int hl = wave >> 1, ks = wave & 1;
  const int h = hp * 2 + hl;
  const int hi = lane >> 5, l31 = lane & 31;
  // Q B-fragments: B[k][q], col=q=lane&31, k = m*16 + hi*8 + e
  bv8 qf[16];
  {
    const unsigned short* qp = q + ((size_t)(b * HH + h) * SS + i0 + l31) * 256;
#pragma unroll
    for (int m = 0; m < 16; ++m) qf[m] = *(const bv8*)(qp + m * 16 + hi * 8);
  }
  fv16 po[8] = {};
  float lsp = 0.f;
  const int t0 = (i0 >= WIN) ? ((i0 - WIN + 1) >> 6) : 0;
  const int t1 = i0 >> 6;
  const unsigned short* kb = kg + (size_t)b * SS * 256;
  const unsigned short* vb = vtg + (size_t)b * 256 * SS;
  const int krow = ks * 32 + l31;        // K-frag row (key within 64-tile)
  const int krx = krow & 7;
  const int vrx = l31 & 7;               // V-frag row&7 (d&7 == l31&7)
  const float FSUB = 16.5f * 1.44269504f;
  for (int t = t0; t <= t1; ++t) {
    if (t > t0) __syncthreads();         // all 4 waves done reading prev tile
    {  // ---- stage K (64x512B) + V^T (256x128B), both-sides XOR swizzle ----
      const unsigned short* kbase = kb + (size_t)t * 64 * 256;
#pragma unroll
      for (int c = 0; c < 8; ++c) {
        int sid = c * 256 + tid;
        int row = sid >> 5, s = sid & 31;
        gld16(kbase + (size_t)row * 256 + ((s ^ (row & 7)) * 8),
              kt + (c * 256 + wave * 64) * 8);
      }
      const unsigned short* vbase = vb + (size_t)t * 64;
#pragma unroll
      for (int c = 0; c < 8; ++c) {
        int sid = c * 256 + tid;
        int d_ = sid >> 3, s = sid & 7;
        gld16(vbase + (size_t)d_ * SS + ((s ^ (d_ & 7)) * 8),
              vl + (c * 256 + wave * 64) * 8);
      }
    }
    __syncthreads();   // vmcnt(0) drain -> tile ready (other block computes now)
    // ---- QK^T (swapped): S^T[key][q] ----
    fv16 sa = {};
    const unsigned short* ktp = kt + krow * 256;
    __builtin_amdgcn_s_setprio(1);
#pragma unroll
    for (int m = 0; m < 16; ++m) {
      bv8 kf = *(const bv8*)(ktp + (((m * 2 + hi) ^ krx) * 8));
      sa = __builtin_amdgcn_mfma_f32_32x32x16_bf16(kf, qf[m], sa, 0, 0, 0);
    }
    __builtin_amdgcn_s_setprio(0);
    // ---- mask + exp2 (fixed max) ----
    const int kb0 = t * 64 + ks * 32;
    const bool nm = (kb0 + 31 > i0) || (i0 + 31 - kb0 >= WIN);
    if (nm) {
      const int qa = i0 + l31;
#pragma unroll
      for (int r = 0; r < 16; ++r) {
        int j = kb0 + (r & 3) + 8 * (r >> 2) + 4 * hi;
        if (j > qa || qa - j >= WIN) sa[r] = -1e30f;
      }
    }
    unsigned a[8];
#pragma unroll
    for (int i = 0; i < 8; ++i) {
      float e0 = exp2f(sa[2 * i] - FSUB);
      float e1 = exp2f(sa[2 * i + 1] - FSUB);
      lsp += e0 + e1;
      a[i] = pk2(e0, e1);
    }
    // ---- P^T B-frag assembly via permlane32_swap + PV ----
    __builtin_amdgcn_s_setprio(1);
#pragma unroll
    for (int m2 = 0; m2 < 2; ++m2) {
      auto r02 = __builtin_amdgcn_permlane32_swap(a[m2 * 4 + 0], a[m2 * 4 + 2], false, false);
      auto r13 = __builtin_amdgcn_permlane32_swap(a[m2 * 4 + 1], a[m2 * 4 + 3], false, false);
      union { unsigned u[4]; bv8 v; } pf;
      pf.u[0] = r02[0]; pf.u[1] = r13[0]; pf.u[2] = r02[1]; pf.u[3] = r13[1];
      const int slot = (ks * 4 + m2 * 2 + hi) ^ vrx;
#pragma unroll
      for (int ds_ = 0; ds_ < 8; ++ds_) {
        bv8 vf = *(const bv8*)(vl + (ds_ * 32 + l31) * 64 + slot * 8);
        po[ds_] = __builtin_amdgcn_mfma_f32_32x32x16_bf16(vf, pf.v, po[ds_], 0, 0, 0);
      }
    }
    __builtin_amdgcn_s_setprio(0);
  }
  // ---- combine the two key-halves (fixed-max partials are linear) ----
  float lsfull = lsp + __shfl_xor(lsp, 32, 64);
  __syncthreads();
  unsigned* cb = (unsigned*)kt;          // [2][32] rows x 133 u32 (bf16 pairs)
  if (ks == 1) {
#pragma unroll
    for (int ds_ = 0; ds_ < 8; ++ds_)
#pragma unroll
      for (int j = 0; j < 4; ++j) {
        int d0 = ds_ * 32 + 8 * j + 4 * hi;
        cb[(hl * 32 + l31) * 133 + (d0 >> 1)] = pk2(po[ds_][4 * j], po[ds_][4 * j + 1]);
        cb[(hl * 32 + l31) * 133 + (d0 >> 1) + 1] = pk2(po[ds_][4 * j + 2], po[ds_][4 * j + 3]);
      }
    if (lane < 32) lsb[hl][lane] = lsfull;
  }
  __syncthreads();
  if (ks == 0) {
    float total = lsfull + lsb[hl][l31];
    float inv = 1.0f / total;
    unsigned short* op = att + ((size_t)b * SS + i0 + l31) * 1024 + h * 256;
#pragma unroll
    for (int ds_ = 0; ds_ < 8; ++ds_)
#pragma unroll
      for (int j = 0; j < 4; ++j) {
        int d0 = ds_ * 32 + 8 * j + 4 * hi;
        unsigned u0 = cb[(hl * 32 + l31) * 133 + (d0 >> 1)];
        unsigned u1 = cb[(hl * 32 + l31) * 133 + (d0 >> 1) + 1];
        ushort4 o;
        o.x = f2b((po[ds_][4 * j] + b2f((unsigned short)(u0 & 0xffff))) * inv);
        o.y = f2b((po[ds_][4 * j + 1] + b2f((unsigned short)(u0 >> 16))) * inv);
        o.z = f2b((po[ds_][4 * j + 2] + b2f((unsigned short)(u1 & 0xffff))) * inv);
        o.w = f2b((po[ds_][4 * j + 3] + b2f((unsigned short)(u1 >> 16))) * inv);
        *(ushort4*)(op + d0) = o;
      }
  }
}

extern "C" void kernel_launch(void* const* d_in, const int* in_sizes, int n_in,
                              void* d_out, int out_size, void* d_ws, size_t ws_size,
                              hipStream_t stream) {
  const float* x    = (const float*)d_in[0];
  // d_in[1] = mask (computed analytically)
  const float* cosp = (const float*)d_in[2];
  const float* sinp = (const float*)d_in[3];
  const float* Wq   = (const float*)d_in[4];
  const float* Wk   = (const float*)d_in[5];
  const float* Wv   = (const float*)d_in[6];
  const float* Wo   = (const float*)d_in[7];
  const float* qsc  = (const float*)d_in[8];
  const float* ksc  = (const float*)d_in[9];
  float* out = (float*)d_out;
  char* ws = (char*)d_ws;

  unsigned short* xb   = (unsigned short*)(ws);               // 8192x640 bf16
  unsigned short* wqkv = (unsigned short*)(ws + 10485760);    // 1536x640 bf16 (W^T)
  unsigned short* wo   = (unsigned short*)(ws + 12451840);    // 640x1024 bf16 (Wo^T)
  unsigned short* qkv  = (unsigned short*)(ws + 13762560);    // 8192x1536 bf16
  unsigned short* qb   = (unsigned short*)(ws + 38928384);    // (B,H,S,D) bf16
  unsigned short* kbuf = (unsigned short*)(ws + 55705600);    // (B,S,D) bf16
  unsigned short* vt   = (unsigned short*)(ws + 59899904);    // (B,D,S) bf16
  unsigned short* attb = (unsigned short*)(ws + 64094208);    // (B,S,H*D) bf16

  k_cast_bf16<<<5120, 256, 0, stream>>>(x, xb, 1310720);
  k_transpose_bf16<float><<<dim3(20, 32), 256, 0, stream>>>(Wq, wqkv, 1024, 640);
  k_transpose_bf16<float><<<dim3(20, 8), 256, 0, stream>>>(Wk, wqkv + 1024 * 640, 256, 640);
  k_transpose_bf16<float><<<dim3(20, 8), 256, 0, stream>>>(Wv, wqkv + 1280 * 640, 256, 640);
  k_transpose_bf16<float><<<dim3(32, 20), 256, 0, stream>>>(Wo, wo, 640, 1024);
  k_gemm<true, 128><<<768, 256, 0, stream>>>(xb, wqkv, qkv, 8192, 1536, 640, 12);
  k_normrope<<<8192, 320, 0, stream>>>(qkv, cosp, sinp, qsc, ksc, qb, kbuf);
  k_transpose_bf16<unsigned short><<<dim3(128, 8), 256, 0, stream>>>(qkv + 1280, vt, 1536, 4096);
  k_transpose_bf16<unsigned short><<<dim3(128, 8), 256, 0, stream>>>(
      qkv + (size_t)4096 * 1536 + 1280, vt + (size_t)256 * 4096, 1536, 4096);
  k_attn<<<512, 256, 0, stream>>>(qb, kbuf, vt, attb);
  k_gemm<false, 64><<<640, 256, 0, stream>>>(attb, wo, out, 8192, 640, 1024, 10);
}

// Round 9
// 124.506 us; speedup vs baseline: 1.0669x; 1.0431x over previous
//
#include <hip/hip_runtime.h>
#include <hip/hip_bf16.h>
#include <stdint.h>

#define BB 2
#define SS 4096
#define EE 640
#define HH 4
#define DD 256
#define WIN 512

typedef __attribute__((ext_vector_type(8))) short bv8;    // 8 bf16 (4 VGPR)
typedef __attribute__((ext_vector_type(4))) float fv4;
typedef __attribute__((ext_vector_type(16))) float fv16;  // 32x32 accumulator

__device__ __forceinline__ unsigned short f2b(float f) {
  union { float f; unsigned u; } a; a.f = f;
  unsigned r = a.u + 0x7fffu + ((a.u >> 16) & 1u);   // RNE
  return (unsigned short)(r >> 16);
}
__device__ __forceinline__ float b2f(unsigned short s) {
  union { unsigned u; float f; } a; a.u = ((unsigned)s) << 16;
  return a.f;
}
__device__ __forceinline__ unsigned pk2(float lo, float hi_) {
  return (unsigned)f2b(lo) | ((unsigned)f2b(hi_) << 16);
}

typedef const __attribute__((address_space(1))) unsigned int* as1u;
typedef __attribute__((address_space(3))) unsigned int* as3u;
__device__ __forceinline__ void gld16(const unsigned short* g, unsigned short* l) {
  // async global->LDS, 16B/lane; LDS dst = wave-uniform base + lane*16
  __builtin_amdgcn_global_load_lds((as1u)(const void*)g, (as3u)(void*)l, 16, 0, 0);
}

// ---------------- f32 -> bf16 cast (x) ----------------
__global__ __launch_bounds__(256) void k_cast_bf16(const float* __restrict__ src,
                                                   unsigned short* __restrict__ dst, int n4) {
  int i = blockIdx.x * 256 + threadIdx.x;
  if (i >= n4) return;
  fv4 v = ((const fv4*)src)[i];
  ushort4 o; o.x = f2b(v.x); o.y = f2b(v.y); o.z = f2b(v.z); o.w = f2b(v.w);
  ((ushort4*)dst)[i] = o;
}

// ---------------- tiled transpose + cast to bf16 ----------------
template <typename T>
__global__ __launch_bounds__(256) void k_transpose_bf16(const T* __restrict__ src,
    unsigned short* __restrict__ dst, int sstride, int dstride) {
  __shared__ float tile[32][33];
  int r0 = blockIdx.x * 32, c0 = blockIdx.y * 32;
  int t = threadIdx.x;
  int rr = t >> 3, cc = (t & 7) * 4;
  const T* p = src + (size_t)(r0 + rr) * sstride + c0 + cc;
  float v[4];
  if constexpr (sizeof(T) == 4) {
    fv4 x = *(const fv4*)p;
    v[0] = x.x; v[1] = x.y; v[2] = x.z; v[3] = x.w;
  } else {
    ushort4 x = *(const ushort4*)p;
    v[0] = b2f(x.x); v[1] = b2f(x.y); v[2] = b2f(x.z); v[3] = b2f(x.w);
  }
#pragma unroll
  for (int i = 0; i < 4; ++i) tile[cc + i][rr] = v[i];
  __syncthreads();
  ushort4 o;
  o.x = f2b(tile[rr][cc + 0]); o.y = f2b(tile[rr][cc + 1]);
  o.z = f2b(tile[rr][cc + 2]); o.w = f2b(tile[rr][cc + 3]);
  *(ushort4*)(dst + (size_t)(c0 + rr) * dstride + r0 + cc) = o;
}

// ---------------- bf16 GEMM (m97 structure): C(MxN) = A(MxK) * Bt(NxK)^T ----
template <bool OUT_BF16, int BN>
__global__ __launch_bounds__(256) void k_gemm(const unsigned short* __restrict__ A,
    const unsigned short* __restrict__ Bt, void* __restrict__ Cp,
    int M, int N, int K, int nt_n) {
  __shared__ unsigned short la[128 * 32];
  __shared__ unsigned short lb[BN * 32];
  const int bid = blockIdx.x;
  const int gidx = (bid & 7) * (gridDim.x >> 3) + (bid >> 3);
  const int m0 = (gidx / nt_n) * 128, n0 = (gidx % nt_n) * BN;
  const int tid = threadIdx.x, lane = tid & 63, wave = tid >> 6;
  const int g = lane >> 4, lr = lane & 15;
  constexpr int MI = (BN == 128) ? 4 : 2;
  const int wm = (BN == 128) ? (wave >> 1) * 64 : wave * 32;
  const int wn = (BN == 128) ? (wave & 1) * 64 : 0;
  fv4 acc[MI][4] = {};
  const int srow = wave * 32 + (lane >> 2);
  const int sch = (lane & 3) * 8;
  const unsigned short* ga0 = A + (size_t)(m0 + srow) * K + sch;
  unsigned short* lad = la + wave * 1024;
  const int srowb = (BN == 128) ? srow : (wave * 16 + (lane >> 2));
  const unsigned short* gb0 = Bt + (size_t)(n0 + srowb) * K + sch;
  unsigned short* lbd = lb + ((BN == 128) ? wave * 1024 : wave * 512);
  for (int k0 = 0; k0 < K; k0 += 32) {
    __syncthreads();
    gld16(ga0 + k0, lad);
    gld16(ga0 + (size_t)16 * K + k0, lad + 512);
    gld16(gb0 + k0, lbd);
    if constexpr (BN == 128) gld16(gb0 + (size_t)16 * K + k0, lbd + 512);
    __syncthreads();
    bv8 af[MI], bf[4];
#pragma unroll
    for (int mi = 0; mi < MI; ++mi) af[mi] = *(const bv8*)(la + (wm + mi * 16 + lr) * 32 + g * 8);
#pragma unroll
    for (int ni = 0; ni < 4; ++ni) bf[ni] = *(const bv8*)(lb + (wn + ni * 16 + lr) * 32 + g * 8);
    __builtin_amdgcn_s_setprio(1);
#pragma unroll
    for (int mi = 0; mi < MI; ++mi)
#pragma unroll
      for (int ni = 0; ni < 4; ++ni)
        acc[mi][ni] = __builtin_amdgcn_mfma_f32_16x16x32_bf16(af[mi], bf[ni], acc[mi][ni], 0, 0, 0);
    __builtin_amdgcn_s_setprio(0);
  }
#pragma unroll
  for (int mi = 0; mi < MI; ++mi) {
#pragma unroll
    for (int r = 0; r < 4; ++r) {
      size_t row = (size_t)(m0 + wm + mi * 16 + g * 4 + r);
#pragma unroll
      for (int ni = 0; ni < 4; ++ni) {
        int col = n0 + wn + ni * 16 + lr;
        float val = acc[mi][ni][r];
        if constexpr (OUT_BF16)
          ((unsigned short*)Cp)[row * N + col] = f2b(val);
        else
          ((float*)Cp)[row * N + col] = val;
      }
    }
  }
}

// ---------------- rmsnorm + rope, bf16 out ----------------------------------
// q scale folds SCALING (1/16) AND log2(e): attn softmax runs in exp2 domain.
__global__ __launch_bounds__(320) void k_normrope(const unsigned short* __restrict__ qkv,
    const float* __restrict__ cosp, const float* __restrict__ sinp,
    const float* __restrict__ qsc, const float* __restrict__ ksc,
    unsigned short* __restrict__ qo, unsigned short* __restrict__ ko) {
  int m = blockIdx.x;
  int b = m >> 12, s = m & 4095;
  int wave = threadIdx.x >> 6, lane = threadIdx.x & 63;
  bool isq = wave < 4;
  const unsigned short* src = qkv + (size_t)m * 1536 + (isq ? wave * 256 : 1024);
  const float* scp = isq ? qsc : ksc;
  int d0 = lane * 4;
  ushort4 raw = *(const ushort4*)(src + d0);
  float x0 = b2f(raw.x), x1 = b2f(raw.y), x2 = b2f(raw.z), x3 = b2f(raw.w);
  float ss = x0 * x0 + x1 * x1 + x2 * x2 + x3 * x3;
#pragma unroll
  for (int off = 1; off < 64; off <<= 1) ss += __shfl_xor(ss, off, 64);
  float rs = rsqrtf(ss * (1.0f / 256.0f) + 1e-6f);
  fv4 sc = *(const fv4*)(scp + d0);
  float n0 = x0 * rs * (1.0f + sc.x);
  float n1 = x1 * rs * (1.0f + sc.y);
  float n2 = x2 * rs * (1.0f + sc.z);
  float n3 = x3 * rs * (1.0f + sc.w);
  float p0 = __shfl_xor(n0, 32, 64);
  float p1 = __shfl_xor(n1, 32, 64);
  float p2 = __shfl_xor(n2, 32, 64);
  float p3 = __shfl_xor(n3, 32, 64);
  float sgn = (lane < 32) ? -1.0f : 1.0f;
  fv4 c4 = *(const fv4*)(cosp + (size_t)s * 256 + d0);
  fv4 s4 = *(const fv4*)(sinp + (size_t)s * 256 + d0);
  float mult = isq ? (0.0625f * 1.44269504f) : 1.0f;   // SCALING * log2(e) into q
  float o0 = (n0 * c4.x + sgn * p0 * s4.x) * mult;
  float o1 = (n1 * c4.y + sgn * p1 * s4.y) * mult;
  float o2 = (n2 * c4.z + sgn * p2 * s4.z) * mult;
  float o3 = (n3 * c4.w + sgn * p3 * s4.w) * mult;
  ushort4 o; o.x = f2b(o0); o.y = f2b(o1); o.z = f2b(o2); o.w = f2b(o3);
  unsigned short* dst = isq
      ? qo + ((size_t)(b * HH + wave) * SS + s) * 256 + d0
      : ko + ((size_t)b * SS + s) * 256 + d0;
  *(ushort4*)dst = o;
}

// ---------------- flash attention, sliding window 512 ----------------------
// MQA-shared (R6 structure): block = 512 thr = 8 waves = 4 heads x 2 key-
// halves over a 32-q-row slab; K/V staged once serve all 4 heads. 32x32x16
// MFMA, swapped operands (S^T = mfma(K,Q)), in-register P via manual pack +
// permlane32_swap. Softmax in exp2 domain (log2e folded into q); fixed max
// (|score*log2e| <= 23.1, Cauchy-Schwarz on RMSNorm'd vectors). K+V double-
// buffered via global_load_lds with both-sides XOR swizzle.
// T3/T4 counted-vmcnt schedule: raw s_barrier pair per tile, stage(t+1)
// issued between them, s_waitcnt vmcnt(8) (NOT 0) keeps the next tile's 8
// loads in flight across the barrier — stage latency hides under compute.
__global__ __launch_bounds__(512, 2) void k_attn(const unsigned short* __restrict__ q,
    const unsigned short* __restrict__ kg, const unsigned short* __restrict__ vtg,
    unsigned short* __restrict__ att) {
  __shared__ __align__(16) char ldsbuf[133120];   // K/V tiles; reused as combine buf
  __shared__ float lsb[4][32];
  unsigned short* kt = (unsigned short*)ldsbuf;           // [2][64*256]
  unsigned short* vl = (unsigned short*)ldsbuf + 32768;   // [2][256*64]
  const int bid = blockIdx.x;
  const int gidx = (bid & 7) * 32 + (bid >> 3);   // XCD-planar: (h,b) per XCD
  const int b = gidx >> 7;
  const int i0 = (gidx & 127) * 32;
  const int tid = threadIdx.x, wave = tid >> 6, lane = tid & 63;
  const int h = wave >> 1, ks = wave & 1;
  const int hi = lane >> 5, l31 = lane & 31;
  // Q B-fragments: B[k][q], col=q=lane&31, k = m*16 + hi*8 + e
  bv8 qf[16];
  {
    const unsigned short* qp = q + ((size_t)(b * HH + h) * SS + i0 + l31) * 256;
#pragma unroll
    for (int m = 0; m < 16; ++m) qf[m] = *(const bv8*)(qp + m * 16 + hi * 8);
  }
  fv16 po[8] = {};
  float lsp = 0.f;
  const int t0 = (i0 >= WIN) ? ((i0 - WIN + 1) >> 6) : 0;
  const int t1 = i0 >> 6;
  const unsigned short* kb = kg + (size_t)b * SS * 256;
  const unsigned short* vb = vtg + (size_t)b * 256 * SS;
  // K stage: 64 rows x 512B = 2048 slots; LDS slot s of row r <- global chunk s^(r&7)
  auto stageK = [&](int t, int pp) {
    const unsigned short* kbase = kb + (size_t)t * 64 * 256;
    unsigned short* dst = kt + pp * 16384;
#pragma unroll
    for (int c = 0; c < 4; ++c) {
      int slot = c * 512 + tid;
      int row = slot >> 5, s = slot & 31;
      gld16(kbase + (size_t)row * 256 + ((s ^ (row & 7)) * 8),
            dst + (c * 512 + wave * 64) * 8);
    }
  };
  // V stage: 256 d-rows x 128B = 2048 slots; slot s of row d <- chunk s^(d&7)
  auto stageV = [&](int t, int pp) {
    const unsigned short* vbase = vb + (size_t)t * 64;
    unsigned short* dst = vl + pp * 16384;
#pragma unroll
    for (int c = 0; c < 4; ++c) {
      int slot = c * 512 + tid;
      int d_ = slot >> 3, s = slot & 7;
      gld16(vbase + (size_t)d_ * SS + ((s ^ (d_ & 7)) * 8),
            dst + (c * 512 + wave * 64) * 8);
    }
  };
  stageK(t0, 0); stageV(t0, 0);
  __syncthreads();   // prologue: retire Q-loads + stage(t0) (once; settles scores)
  int p = 0;
  const int krow = ks * 32 + l31;        // K-frag row (key within 64-tile)
  const int krx = krow & 7;
  const int vrx = l31 & 7;               // V-frag row&7 (d&7 == l31&7)
  const float FSUB = 16.5f * 1.44269504f;
  for (int t = t0; t <= t1; ++t) {
    if (t > t0) __builtin_amdgcn_s_barrier();   // #1: all waves done reading p^1
    if (t < t1) {
      stageK(t + 1, p ^ 1); stageV(t + 1, p ^ 1);   // 8 gld16/wave into p^1
      asm volatile("s_waitcnt vmcnt(8)" ::: "memory");   // stage(t) done; t+1 in flight
    } else {
      asm volatile("s_waitcnt vmcnt(0)" ::: "memory");   // last tile: full drain
    }
    __builtin_amdgcn_sched_barrier(0);
    __builtin_amdgcn_s_barrier();               // #2: tile t visible to all waves
    // ---- QK^T (swapped): S^T[key][q] ----
    fv16 sa = {};
    const unsigned short* ktp = kt + p * 16384 + krow * 256;
    __builtin_amdgcn_s_setprio(1);
#pragma unroll
    for (int m = 0; m < 16; ++m) {
      bv8 kf = *(const bv8*)(ktp + (((m * 2 + hi) ^ krx) * 8));
      sa = __builtin_amdgcn_mfma_f32_32x32x16_bf16(kf, qf[m], sa, 0, 0, 0);
    }
    __builtin_amdgcn_s_setprio(0);
    // ---- mask + exp2 (fixed max) ----
    const int kb0 = t * 64 + ks * 32;
    const bool nm = (kb0 + 31 > i0) || (i0 + 31 - kb0 >= WIN);
    if (nm) {
      const int qa = i0 + l31;
#pragma unroll
      for (int r = 0; r < 16; ++r) {
        int j = kb0 + (r & 3) + 8 * (r >> 2) + 4 * hi;
        if (j > qa || qa - j >= WIN) sa[r] = -1e30f;
      }
    }
    unsigned a[8];
#pragma unroll
    for (int i = 0; i < 8; ++i) {
      float e0 = exp2f(sa[2 * i] - FSUB);
      float e1 = exp2f(sa[2 * i + 1] - FSUB);
      lsp += e0 + e1;
      a[i] = pk2(e0, e1);
    }
    // ---- P^T B-frag assembly via permlane32_swap + PV ----
    const unsigned short* vlp = vl + p * 16384;
    __builtin_amdgcn_s_setprio(1);
#pragma unroll
    for (int m2 = 0; m2 < 2; ++m2) {
      auto r02 = __builtin_amdgcn_permlane32_swap(a[m2 * 4 + 0], a[m2 * 4 + 2], false, false);
      auto r13 = __builtin_amdgcn_permlane32_swap(a[m2 * 4 + 1], a[m2 * 4 + 3], false, false);
      union { unsigned u[4]; bv8 v; } pf;
      pf.u[0] = r02[0]; pf.u[1] = r13[0]; pf.u[2] = r02[1]; pf.u[3] = r13[1];
      const int slot = (ks * 4 + m2 * 2 + hi) ^ vrx;
#pragma unroll
      for (int ds_ = 0; ds_ < 8; ++ds_) {
        bv8 vf = *(const bv8*)(vlp + (ds_ * 32 + l31) * 64 + slot * 8);
        po[ds_] = __builtin_amdgcn_mfma_f32_32x32x16_bf16(vf, pf.v, po[ds_], 0, 0, 0);
      }
    }
    __builtin_amdgcn_s_setprio(0);
    p ^= 1;
  }
  // ---- combine the two key-halves (fixed-max partials are linear) ----
  float lsfull = lsp + __shfl_xor(lsp, 32, 64);
  __syncthreads();
  float* cb = (float*)ldsbuf;            // rows 128 (h*32+q) x stride 260 f32
  if (ks == 1) {
#pragma unroll
    for (int ds_ = 0; ds_ < 8; ++ds_)
#pragma unroll
      for (int j = 0; j < 4; ++j) {
        int d0 = ds_ * 32 + 8 * j + 4 * hi;
        fv4 v4; v4[0] = po[ds_][4 * j]; v4[1] = po[ds_][4 * j + 1];
        v4[2] = po[ds_][4 * j + 2]; v4[3] = po[ds_][4 * j + 3];
        *(fv4*)(cb + (h * 32 + l31) * 260 + d0) = v4;
      }
    if (lane < 32) lsb[h][lane] = lsfull;
  }
  __syncthreads();
  if (ks == 0) {
    float total = lsfull + lsb[h][l31];
    float inv = 1.0f / total;
    unsigned short* op = att + ((size_t)b * SS + i0 + l31) * 1024 + h * 256;
#pragma unroll
    for (int ds_ = 0; ds_ < 8; ++ds_)
#pragma unroll
      for (int j = 0; j < 4; ++j) {
        int d0 = ds_ * 32 + 8 * j + 4 * hi;
        fv4 v4 = *(const fv4*)(cb + (h * 32 + l31) * 260 + d0);
        ushort4 o;
        o.x = f2b((po[ds_][4 * j] + v4[0]) * inv);
        o.y = f2b((po[ds_][4 * j + 1] + v4[1]) * inv);
        o.z = f2b((po[ds_][4 * j + 2] + v4[2]) * inv);
        o.w = f2b((po[ds_][4 * j + 3] + v4[3]) * inv);
        *(ushort4*)(op + d0) = o;
      }
  }
}

extern "C" void kernel_launch(void* const* d_in, const int* in_sizes, int n_in,
                              void* d_out, int out_size, void* d_ws, size_t ws_size,
                              hipStream_t stream) {
  const float* x    = (const float*)d_in[0];
  // d_in[1] = mask (computed analytically)
  const float* cosp = (const float*)d_in[2];
  const float* sinp = (const float*)d_in[3];
  const float* Wq   = (const float*)d_in[4];
  const float* Wk   = (const float*)d_in[5];
  const float* Wv   = (const float*)d_in[6];
  const float* Wo   = (const float*)d_in[7];
  const float* qsc  = (const float*)d_in[8];
  const float* ksc  = (const float*)d_in[9];
  float* out = (float*)d_out;
  char* ws = (char*)d_ws;

  unsigned short* xb   = (unsigned short*)(ws);               // 8192x640 bf16
  unsigned short* wqkv = (unsigned short*)(ws + 10485760);    // 1536x640 bf16 (W^T)
  unsigned short* wo   = (unsigned short*)(ws + 12451840);    // 640x1024 bf16 (Wo^T)
  unsigned short* qkv  = (unsigned short*)(ws + 13762560);    // 8192x1536 bf16
  unsigned short* qb   = (unsigned short*)(ws + 38928384);    // (B,H,S,D) bf16
  unsigned short* kbuf = (unsigned short*)(ws + 55705600);    // (B,S,D) bf16
  unsigned short* vt   = (unsigned short*)(ws + 59899904);    // (B,D,S) bf16
  unsigned short* attb = (unsigned short*)(ws + 64094208);    // (B,S,H*D) bf16

  k_cast_bf16<<<5120, 256, 0, stream>>>(x, xb, 1310720);
  k_transpose_bf16<float><<<dim3(20, 32), 256, 0, stream>>>(Wq, wqkv, 1024, 640);
  k_transpose_bf16<float><<<dim3(20, 8), 256, 0, stream>>>(Wk, wqkv + 1024 * 640, 256, 640);
  k_transpose_bf16<float><<<dim3(20, 8), 256, 0, stream>>>(Wv, wqkv + 1280 * 640, 256, 640);
  k_transpose_bf16<float><<<dim3(32, 20), 256, 0, stream>>>(Wo, wo, 640, 1024);
  k_gemm<true, 128><<<768, 256, 0, stream>>>(xb, wqkv, qkv, 8192, 1536, 640, 12);
  k_normrope<<<8192, 320, 0, stream>>>(qkv, cosp, sinp, qsc, ksc, qb, kbuf);
  k_transpose_bf16<unsigned short><<<dim3(128, 8), 256, 0, stream>>>(qkv + 1280, vt, 1536, 4096);
  k_transpose_bf16<unsigned short><<<dim3(128, 8), 256, 0, stream>>>(
      qkv + (size_t)4096 * 1536 + 1280, vt + (size_t)256 * 4096, 1536, 4096);
  k_attn<<<256, 512, 0, stream>>>(qb, kbuf, vt, attb);
  k_gemm<false, 64><<<640, 256, 0, stream>>>(attb, wo, out, 8192, 640, 1024, 10);
}

// Round 10
// 115.042 us; speedup vs baseline: 1.1547x; 1.0823x over previous
//
#include <hip/hip_runtime.h>
#include <hip/hip_bf16.h>
#include <stdint.h>

#define BB 2
#define SS 4096
#define EE 640
#define HH 4
#define DD 256
#define WIN 512

typedef __attribute__((ext_vector_type(8))) short bv8;    // 8 bf16 (4 VGPR)
typedef __attribute__((ext_vector_type(4))) float fv4;
typedef __attribute__((ext_vector_type(16))) float fv16;  // 32x32 accumulator

__device__ __forceinline__ unsigned short f2b(float f) {
  union { float f; unsigned u; } a; a.f = f;
  unsigned r = a.u + 0x7fffu + ((a.u >> 16) & 1u);   // RNE
  return (unsigned short)(r >> 16);
}
__device__ __forceinline__ float b2f(unsigned short s) {
  union { unsigned u; float f; } a; a.u = ((unsigned)s) << 16;
  return a.f;
}
__device__ __forceinline__ unsigned pk2(float lo, float hi_) {
  return (unsigned)f2b(lo) | ((unsigned)f2b(hi_) << 16);
}

typedef const __attribute__((address_space(1))) unsigned int* as1u;
typedef __attribute__((address_space(3))) unsigned int* as3u;
__device__ __forceinline__ void gld16(const unsigned short* g, unsigned short* l) {
  // async global->LDS, 16B/lane; LDS dst = wave-uniform base + lane*16
  __builtin_amdgcn_global_load_lds((as1u)(const void*)g, (as3u)(void*)l, 16, 0, 0);
}

// ---------------- f32 -> bf16 cast (x) ----------------
__global__ __launch_bounds__(256) void k_cast_bf16(const float* __restrict__ src,
                                                   unsigned short* __restrict__ dst, int n4) {
  int i = blockIdx.x * 256 + threadIdx.x;
  if (i >= n4) return;
  fv4 v = ((const fv4*)src)[i];
  ushort4 o; o.x = f2b(v.x); o.y = f2b(v.y); o.z = f2b(v.z); o.w = f2b(v.w);
  ((ushort4*)dst)[i] = o;
}

// ---------------- merged weight transposes (f32 -> bf16), 32x32 tiles -------
// z=0: Wq (1024x640)->wqkv[0]; z=1: Wk (256x640)->wqkv+1024*640;
// z=2: Wv (256x640)->wqkv+1280*640; z=3: Wo (1024x640 viewed (HD,E))->wo (640x1024)
__global__ __launch_bounds__(256) void k_wtrans(const float* __restrict__ Wq,
    const float* __restrict__ Wk, const float* __restrict__ Wv,
    const float* __restrict__ Wo, unsigned short* __restrict__ wqkv,
    unsigned short* __restrict__ wo) {
  __shared__ float tile[32][33];
  const int z = blockIdx.z, bx = blockIdx.x, by = blockIdx.y;
  const float* src; unsigned short* dst; int ss, ds;
  if (z == 0)      { if (bx >= 20 || by >= 32) return; src = Wq; dst = wqkv;              ss = 1024; ds = 640; }
  else if (z == 1) { if (bx >= 20 || by >= 8)  return; src = Wk; dst = wqkv + 1024 * 640; ss = 256;  ds = 640; }
  else if (z == 2) { if (bx >= 20 || by >= 8)  return; src = Wv; dst = wqkv + 1280 * 640; ss = 256;  ds = 640; }
  else             { if (bx >= 32 || by >= 20) return; src = Wo; dst = wo;                ss = 640;  ds = 1024; }
  int r0 = bx * 32, c0 = by * 32;
  int t = threadIdx.x;
  int rr = t >> 3, cc = (t & 7) * 4;
  fv4 x = *(const fv4*)(src + (size_t)(r0 + rr) * ss + c0 + cc);
#pragma unroll
  for (int i = 0; i < 4; ++i) tile[cc + i][rr] = x[i];
  __syncthreads();
  ushort4 o;
  o.x = f2b(tile[rr][cc + 0]); o.y = f2b(tile[rr][cc + 1]);
  o.z = f2b(tile[rr][cc + 2]); o.w = f2b(tile[rr][cc + 3]);
  *(ushort4*)(dst + (size_t)(c0 + rr) * ds + r0 + cc) = o;
}

// ---------------- merged V transpose (both batches), bf16 32x32 tiles -------
// src: qkv rows (b*4096+s) stride 1536, cols 1280..1536 -> vt[b][d][s]
__global__ __launch_bounds__(256) void k_vtrans(const unsigned short* __restrict__ qkv,
    unsigned short* __restrict__ vt) {
  __shared__ float tile[32][33];
  const int z = blockIdx.z;
  const unsigned short* src = qkv + (size_t)z * 4096 * 1536 + 1280;
  unsigned short* dst = vt + (size_t)z * 256 * 4096;
  int r0 = blockIdx.x * 32, c0 = blockIdx.y * 32;
  int t = threadIdx.x;
  int rr = t >> 3, cc = (t & 7) * 4;
  ushort4 x = *(const ushort4*)(src + (size_t)(r0 + rr) * 1536 + c0 + cc);
  tile[cc + 0][rr] = b2f(x.x); tile[cc + 1][rr] = b2f(x.y);
  tile[cc + 2][rr] = b2f(x.z); tile[cc + 3][rr] = b2f(x.w);
  __syncthreads();
  ushort4 o;
  o.x = f2b(tile[rr][cc + 0]); o.y = f2b(tile[rr][cc + 1]);
  o.z = f2b(tile[rr][cc + 2]); o.w = f2b(tile[rr][cc + 3]);
  *(ushort4*)(dst + (size_t)(c0 + rr) * 4096 + r0 + cc) = o;
}

// ---------------- bf16 GEMM: C(MxN) = A(MxK) * Bt(NxK)^T --------------------
// 128xBN tile, BK=32, DOUBLE-BUFFERED LDS with counted vmcnt (T3/T4): stage
// (k+1) issued between raw barriers; vmcnt(N>0) keeps next tile's loads in
// flight across the barrier. Linear LDS (64B rows), global_load_lds width-16,
// XCD-chunked grid swizzle.
template <bool OUT_BF16, int BN>
__global__ __launch_bounds__(256) void k_gemm(const unsigned short* __restrict__ A,
    const unsigned short* __restrict__ Bt, void* __restrict__ Cp,
    int M, int N, int K, int nt_n) {
  __shared__ unsigned short la[2][128 * 32];
  __shared__ unsigned short lb[2][BN * 32];
  const int bid = blockIdx.x;
  const int gidx = (bid & 7) * (gridDim.x >> 3) + (bid >> 3);
  const int m0 = (gidx / nt_n) * 128, n0 = (gidx % nt_n) * BN;
  const int tid = threadIdx.x, lane = tid & 63, wave = tid >> 6;
  const int g = lane >> 4, lr = lane & 15;
  constexpr int MI = (BN == 128) ? 4 : 2;
  const int wm = (BN == 128) ? (wave >> 1) * 64 : wave * 32;
  const int wn = (BN == 128) ? (wave & 1) * 64 : 0;
  fv4 acc[MI][4] = {};
  const int srow = wave * 32 + (lane >> 2);
  const int sch = (lane & 3) * 8;
  const unsigned short* ga0 = A + (size_t)(m0 + srow) * K + sch;
  const int srowb = (BN == 128) ? srow : (wave * 16 + (lane >> 2));
  const unsigned short* gb0 = Bt + (size_t)(n0 + srowb) * K + sch;
  const int NIT = K >> 5;
  auto stage = [&](int k0, int pp) {
    unsigned short* lad = la[pp] + wave * 1024;
    unsigned short* lbd = lb[pp] + ((BN == 128) ? wave * 1024 : wave * 512);
    gld16(ga0 + k0, lad);
    gld16(ga0 + (size_t)16 * K + k0, lad + 512);
    gld16(gb0 + k0, lbd);
    if constexpr (BN == 128) gld16(gb0 + (size_t)16 * K + k0, lbd + 512);
  };
  stage(0, 0);
  for (int it = 0; it < NIT; ++it) {
    const int p = it & 1;
    if (it > 0) __builtin_amdgcn_s_barrier();          // readers done with p^1
    if (it + 1 < NIT) {
      stage((it + 1) * 32, p ^ 1);                     // prefetch into p^1
      if constexpr (BN == 128)
        asm volatile("s_waitcnt vmcnt(4)" ::: "memory");   // stage(it) landed
      else
        asm volatile("s_waitcnt vmcnt(3)" ::: "memory");
    } else {
      asm volatile("s_waitcnt vmcnt(0)" ::: "memory");
    }
    __builtin_amdgcn_sched_barrier(0);
    __builtin_amdgcn_s_barrier();                      // tile it visible
    bv8 af[MI], bf[4];
#pragma unroll
    for (int mi = 0; mi < MI; ++mi)
      af[mi] = *(const bv8*)(la[p] + (wm + mi * 16 + lr) * 32 + g * 8);
#pragma unroll
    for (int ni = 0; ni < 4; ++ni)
      bf[ni] = *(const bv8*)(lb[p] + (wn + ni * 16 + lr) * 32 + g * 8);
    __builtin_amdgcn_s_setprio(1);
#pragma unroll
    for (int mi = 0; mi < MI; ++mi)
#pragma unroll
      for (int ni = 0; ni < 4; ++ni)
        acc[mi][ni] = __builtin_amdgcn_mfma_f32_16x16x32_bf16(af[mi], bf[ni], acc[mi][ni], 0, 0, 0);
    __builtin_amdgcn_s_setprio(0);
  }
#pragma unroll
  for (int mi = 0; mi < MI; ++mi) {
#pragma unroll
    for (int r = 0; r < 4; ++r) {
      size_t row = (size_t)(m0 + wm + mi * 16 + g * 4 + r);
#pragma unroll
      for (int ni = 0; ni < 4; ++ni) {
        int col = n0 + wn + ni * 16 + lr;
        float val = acc[mi][ni][r];
        if constexpr (OUT_BF16)
          ((unsigned short*)Cp)[row * N + col] = f2b(val);
        else
          ((float*)Cp)[row * N + col] = val;
      }
    }
  }
}

// ---------------- rmsnorm + rope, bf16 out ----------------------------------
// q scale folds SCALING (1/16) AND log2(e): attn softmax runs in exp2 domain.
__global__ __launch_bounds__(320) void k_normrope(const unsigned short* __restrict__ qkv,
    const float* __restrict__ cosp, const float* __restrict__ sinp,
    const float* __restrict__ qsc, const float* __restrict__ ksc,
    unsigned short* __restrict__ qo, unsigned short* __restrict__ ko) {
  int m = blockIdx.x;
  int b = m >> 12, s = m & 4095;
  int wave = threadIdx.x >> 6, lane = threadIdx.x & 63;
  bool isq = wave < 4;
  const unsigned short* src = qkv + (size_t)m * 1536 + (isq ? wave * 256 : 1024);
  const float* scp = isq ? qsc : ksc;
  int d0 = lane * 4;
  ushort4 raw = *(const ushort4*)(src + d0);
  float x0 = b2f(raw.x), x1 = b2f(raw.y), x2 = b2f(raw.z), x3 = b2f(raw.w);
  float ss = x0 * x0 + x1 * x1 + x2 * x2 + x3 * x3;
#pragma unroll
  for (int off = 1; off < 64; off <<= 1) ss += __shfl_xor(ss, off, 64);
  float rs = rsqrtf(ss * (1.0f / 256.0f) + 1e-6f);
  fv4 sc = *(const fv4*)(scp + d0);
  float n0 = x0 * rs * (1.0f + sc.x);
  float n1 = x1 * rs * (1.0f + sc.y);
  float n2 = x2 * rs * (1.0f + sc.z);
  float n3 = x3 * rs * (1.0f + sc.w);
  float p0 = __shfl_xor(n0, 32, 64);
  float p1 = __shfl_xor(n1, 32, 64);
  float p2 = __shfl_xor(n2, 32, 64);
  float p3 = __shfl_xor(n3, 32, 64);
  float sgn = (lane < 32) ? -1.0f : 1.0f;
  fv4 c4 = *(const fv4*)(cosp + (size_t)s * 256 + d0);
  fv4 s4 = *(const fv4*)(sinp + (size_t)s * 256 + d0);
  float mult = isq ? (0.0625f * 1.44269504f) : 1.0f;   // SCALING * log2(e) into q
  float o0 = (n0 * c4.x + sgn * p0 * s4.x) * mult;
  float o1 = (n1 * c4.y + sgn * p1 * s4.y) * mult;
  float o2 = (n2 * c4.z + sgn * p2 * s4.z) * mult;
  float o3 = (n3 * c4.w + sgn * p3 * s4.w) * mult;
  ushort4 o; o.x = f2b(o0); o.y = f2b(o1); o.z = f2b(o2); o.w = f2b(o3);
  unsigned short* dst = isq
      ? qo + ((size_t)(b * HH + wave) * SS + s) * 256 + d0
      : ko + ((size_t)b * SS + s) * 256 + d0;
  *(ushort4*)dst = o;
}

// ---------------- flash attention, sliding window 512 ----------------------
// MQA-shared (R6 structure, best measured): block = 512 thr = 8 waves =
// 4 heads x 2 key-halves over a 32-q-row slab; K/V staged once serve all 4
// heads. 32x32x16 MFMA, swapped operands (S^T = mfma(K,Q)), in-register P via
// manual pack + permlane32_swap. Softmax in exp2 domain (log2e folded into q);
// fixed max (|score*log2e| <= 23.1, Cauchy-Schwarz on RMSNorm'd vectors).
// K+V double-buffered via global_load_lds with both-sides XOR swizzle;
// __syncthreads-top loop (already depth-1 pipelined: at each sync the only
// outstanding VMEM is stage(t+1) — R9 measured counted-vmcnt as equal).
__global__ __launch_bounds__(512, 2) void k_attn(const unsigned short* __restrict__ q,
    const unsigned short* __restrict__ kg, const unsigned short* __restrict__ vtg,
    unsigned short* __restrict__ att) {
  __shared__ __align__(16) char ldsbuf[133120];   // K/V tiles; reused as combine buf
  __shared__ float lsb[4][32];
  unsigned short* kt = (unsigned short*)ldsbuf;           // [2][64*256]
  unsigned short* vl = (unsigned short*)ldsbuf + 32768;   // [2][256*64]
  const int bid = blockIdx.x;
  const int gidx = (bid & 7) * 32 + (bid >> 3);   // XCD-planar: (h,b) per XCD
  const int b = gidx >> 7;
  const int i0 = (gidx & 127) * 32;
  const int tid = threadIdx.x, wave = tid >> 6, lane = tid & 63;
  const int h = wave >> 1, ks = wave & 1;
  const int hi = lane >> 5, l31 = lane & 31;
  // Q B-fragments: B[k][q], col=q=lane&31, k = m*16 + hi*8 + e
  bv8 qf[16];
  {
    const unsigned short* qp = q + ((size_t)(b * HH + h) * SS + i0 + l31) * 256;
#pragma unroll
    for (int m = 0; m < 16; ++m) qf[m] = *(const bv8*)(qp + m * 16 + hi * 8);
  }
  fv16 po[8] = {};
  float lsp = 0.f;
  const int t0 = (i0 >= WIN) ? ((i0 - WIN + 1) >> 6) : 0;
  const int t1 = i0 >> 6;
  const unsigned short* kb = kg + (size_t)b * SS * 256;
  const unsigned short* vb = vtg + (size_t)b * 256 * SS;
  // K stage: 64 rows x 512B = 2048 slots; LDS slot s of row r <- global chunk s^(r&7)
  auto stageK = [&](int t, int pp) {
    const unsigned short* kbase = kb + (size_t)t * 64 * 256;
    unsigned short* dst = kt + pp * 16384;
#pragma unroll
    for (int c = 0; c < 4; ++c) {
      int slot = c * 512 + tid;
      int row = slot >> 5, s = slot & 31;
      gld16(kbase + (size_t)row * 256 + ((s ^ (row & 7)) * 8),
            dst + (c * 512 + wave * 64) * 8);
    }
  };
  // V stage: 256 d-rows x 128B = 2048 slots; slot s of row d <- chunk s^(d&7)
  auto stageV = [&](int t, int pp) {
    const unsigned short* vbase = vb + (size_t)t * 64;
    unsigned short* dst = vl + pp * 16384;
#pragma unroll
    for (int c = 0; c < 4; ++c) {
      int slot = c * 512 + tid;
      int d_ = slot >> 3, s = slot & 7;
      gld16(vbase + (size_t)d_ * SS + ((s ^ (d_ & 7)) * 8),
            dst + (c * 512 + wave * 64) * 8);
    }
  };
  stageK(t0, 0); stageV(t0, 0);
  int p = 0;
  const int krow = ks * 32 + l31;        // K-frag row (key within 64-tile)
  const int krx = krow & 7;
  const int vrx = l31 & 7;               // V-frag row&7 (d&7 == l31&7)
  const float FSUB = 16.5f * 1.44269504f;
  for (int t = t0; t <= t1; ++t) {
    __syncthreads();   // drains staging of buf p; prior iter's reads of p^1 done
    if (t < t1) { stageK(t + 1, p ^ 1); stageV(t + 1, p ^ 1); }
    // ---- QK^T (swapped): S^T[key][q] ----
    fv16 sa = {};
    const unsigned short* ktp = kt + p * 16384 + krow * 256;
    __builtin_amdgcn_s_setprio(1);
#pragma unroll
    for (int m = 0; m < 16; ++m) {
      bv8 kf = *(const bv8*)(ktp + (((m * 2 + hi) ^ krx) * 8));
      sa = __builtin_amdgcn_mfma_f32_32x32x16_bf16(kf, qf[m], sa, 0, 0, 0);
    }
    __builtin_amdgcn_s_setprio(0);
    // ---- mask + exp2 (fixed max) ----
    const int kb0 = t * 64 + ks * 32;
    const bool nm = (kb0 + 31 > i0) || (i0 + 31 - kb0 >= WIN);
    if (nm) {
      const int qa = i0 + l31;
#pragma unroll
      for (int r = 0; r < 16; ++r) {
        int j = kb0 + (r & 3) + 8 * (r >> 2) + 4 * hi;
        if (j > qa || qa - j >= WIN) sa[r] = -1e30f;
      }
    }
    unsigned a[8];
#pragma unroll
    for (int i = 0; i < 8; ++i) {
      float e0 = exp2f(sa[2 * i] - FSUB);
      float e1 = exp2f(sa[2 * i + 1] - FSUB);
      lsp += e0 + e1;
      a[i] = pk2(e0, e1);
    }
    // ---- P^T B-frag assembly via permlane32_swap + PV ----
    const unsigned short* vlp = vl + p * 16384;
    __builtin_amdgcn_s_setprio(1);
#pragma unroll
    for (int m2 = 0; m2 < 2; ++m2) {
      auto r02 = __builtin_amdgcn_permlane32_swap(a[m2 * 4 + 0], a[m2 * 4 + 2], false, false);
      auto r13 = __builtin_amdgcn_permlane32_swap(a[m2 * 4 + 1], a[m2 * 4 + 3], false, false);
      union { unsigned u[4]; bv8 v; } pf;
      pf.u[0] = r02[0]; pf.u[1] = r13[0]; pf.u[2] = r02[1]; pf.u[3] = r13[1];
      const int slot = (ks * 4 + m2 * 2 + hi) ^ vrx;
#pragma unroll
      for (int ds_ = 0; ds_ < 8; ++ds_) {
        bv8 vf = *(const bv8*)(vlp + (ds_ * 32 + l31) * 64 + slot * 8);
        po[ds_] = __builtin_amdgcn_mfma_f32_32x32x16_bf16(vf, pf.v, po[ds_], 0, 0, 0);
      }
    }
    __builtin_amdgcn_s_setprio(0);
    p ^= 1;
  }
  // ---- combine the two key-halves (fixed-max partials are linear) ----
  float lsfull = lsp + __shfl_xor(lsp, 32, 64);
  __syncthreads();
  float* cb = (float*)ldsbuf;            // rows 128 (h*32+q) x stride 260 f32
  if (ks == 1) {
#pragma unroll
    for (int ds_ = 0; ds_ < 8; ++ds_)
#pragma unroll
      for (int j = 0; j < 4; ++j) {
        int d0 = ds_ * 32 + 8 * j + 4 * hi;
        fv4 v4; v4[0] = po[ds_][4 * j]; v4[1] = po[ds_][4 * j + 1];
        v4[2] = po[ds_][4 * j + 2]; v4[3] = po[ds_][4 * j + 3];
        *(fv4*)(cb + (h * 32 + l31) * 260 + d0) = v4;
      }
    if (lane < 32) lsb[h][lane] = lsfull;
  }
  __syncthreads();
  if (ks == 0) {
    float total = lsfull + lsb[h][l31];
    float inv = 1.0f / total;
    unsigned short* op = att + ((size_t)b * SS + i0 + l31) * 1024 + h * 256;
#pragma unroll
    for (int ds_ = 0; ds_ < 8; ++ds_)
#pragma unroll
      for (int j = 0; j < 4; ++j) {
        int d0 = ds_ * 32 + 8 * j + 4 * hi;
        fv4 v4 = *(const fv4*)(cb + (h * 32 + l31) * 260 + d0);
        ushort4 o;
        o.x = f2b((po[ds_][4 * j] + v4[0]) * inv);
        o.y = f2b((po[ds_][4 * j + 1] + v4[1]) * inv);
        o.z = f2b((po[ds_][4 * j + 2] + v4[2]) * inv);
        o.w = f2b((po[ds_][4 * j + 3] + v4[3]) * inv);
        *(ushort4*)(op + d0) = o;
      }
  }
}

extern "C" void kernel_launch(void* const* d_in, const int* in_sizes, int n_in,
                              void* d_out, int out_size, void* d_ws, size_t ws_size,
                              hipStream_t stream) {
  const float* x    = (const float*)d_in[0];
  // d_in[1] = mask (computed analytically)
  const float* cosp = (const float*)d_in[2];
  const float* sinp = (const float*)d_in[3];
  const float* Wq   = (const float*)d_in[4];
  const float* Wk   = (const float*)d_in[5];
  const float* Wv   = (const float*)d_in[6];
  const float* Wo   = (const float*)d_in[7];
  const float* qsc  = (const float*)d_in[8];
  const float* ksc  = (const float*)d_in[9];
  float* out = (float*)d_out;
  char* ws = (char*)d_ws;

  unsigned short* xb   = (unsigned short*)(ws);               // 8192x640 bf16
  unsigned short* wqkv = (unsigned short*)(ws + 10485760);    // 1536x640 bf16 (W^T)
  unsigned short* wo   = (unsigned short*)(ws + 12451840);    // 640x1024 bf16 (Wo^T)
  unsigned short* qkv  = (unsigned short*)(ws + 13762560);    // 8192x1536 bf16
  unsigned short* qb   = (unsigned short*)(ws + 38928384);    // (B,H,S,D) bf16
  unsigned short* kbuf = (unsigned short*)(ws + 55705600);    // (B,S,D) bf16
  unsigned short* vt   = (unsigned short*)(ws + 59899904);    // (B,D,S) bf16
  unsigned short* attb = (unsigned short*)(ws + 64094208);    // (B,S,H*D) bf16

  k_cast_bf16<<<5120, 256, 0, stream>>>(x, xb, 1310720);
  k_wtrans<<<dim3(32, 32, 4), 256, 0, stream>>>(Wq, Wk, Wv, Wo, wqkv, wo);
  k_gemm<true, 128><<<768, 256, 0, stream>>>(xb, wqkv, qkv, 8192, 1536, 640, 12);
  k_normrope<<<8192, 320, 0, stream>>>(qkv, cosp, sinp, qsc, ksc, qb, kbuf);
  k_vtrans<<<dim3(128, 8, 2), 256, 0, stream>>>(qkv, vt);
  k_attn<<<256, 512, 0, stream>>>(qb, kbuf, vt, attb);
  k_gemm<false, 64><<<640, 256, 0, stream>>>(attb, wo, out, 8192, 640, 1024, 10);
}